// Round 9
// baseline (127.809 us; speedup 1.0000x reference)
//
#include <hip/hip_runtime.h>

#define BATCH 32
#define NROWS 8192
#define IND   128
#define HC    128
#define NEG   0.2f
#define TILES 8                           // row-tiles per wave
#define TROWS 16                          // rows per tile
#define WPB   64                          // wave-units per batch (16 blocks x 4 waves)
#define SLDS  156                         // slab row stride (floats); head h lives at col h*40
#define PART_STRIDE 136                   // 4 M + 4 S + 128 P floats

typedef __attribute__((ext_vector_type(8))) short short8;
typedef __attribute__((ext_vector_type(4))) float f32x4;

#define CFENCE() asm volatile("" ::: "memory")

__device__ __forceinline__ unsigned short f2bf(float f) {
    unsigned u = __float_as_uint(f);
    u += 0x7FFFu + ((u >> 16) & 1u);      // round-to-nearest-even
    return (unsigned short)(u >> 16);
}
__device__ __forceinline__ unsigned pack2(float a, float b) {
    return (unsigned)f2bf(a) | ((unsigned)f2bf(b) << 16);
}

// ---------------- kernel A: x_l for center rows only (B rows) ----------------
__global__ void gat_center(const float* __restrict__ x, const float* __restrict__ Wl,
                           const float* __restrict__ bl, float* __restrict__ xl0)
{
    const int b = blockIdx.x, t = threadIdx.x;   // 128 threads
    __shared__ float xrow[128];
    xrow[t] = x[(size_t)b * NROWS * IND + t];
    __syncthreads();
    float acc = bl[t];
#pragma unroll 16
    for (int k = 0; k < 128; ++k) acc = fmaf(xrow[k], Wl[k * 128 + t], acc);
    xl0[b * 128 + t] = acc;
}

// ---------------- kernel B: wave-autonomous GEMM + fused epilogue ------------
// One prologue barrier; afterwards each wave is fully independent: 16-row
// tiles x all 128 cols, W_r^T in registers, private LDS slab (head-gapped
// layout, >=2-way banks), contiguous 1KB out-stores, lane<->(row,head)
// epilogue with 1 expf/lane.  Zero barriers / vmcnt drains in the loop ->
// waves drift and keep the memory pipes continuously fed.
__global__ __launch_bounds__(256, 2) void gat_main(
    const float* __restrict__ x, const float* __restrict__ Wr,
    const float* __restrict__ br, const float* __restrict__ att,
    const float* __restrict__ xl0, float* __restrict__ out,
    float* __restrict__ part)
{
    const int tid  = threadIdx.x;
    const int lane = tid & 63;
    const int wv   = tid >> 6;
    const int b    = blockIdx.x >> 4;          // 16 blocks per batch
    const int wu   = (blockIdx.x & 15) * 4 + wv;
    const int l15  = lane & 15, ksel = lane >> 4;

    __shared__ unsigned short WrT[128 * 128];  // 32 KB, swizzled, read-only after barrier
    __shared__ float slabs[4][TROWS * SLDS];   // 39 KB, wave-private
    __shared__ float xl0_s[128], att_s[128];
    float* slab = slabs[wv];

    // ---- prologue: WrT swizzled (coalesced), consts
    for (int i = tid; i < 128 * 128; i += 256) {
        int n = i & 127, k = i >> 7;
        WrT[n * 128 + (k ^ ((n & 7) << 3))] = f2bf(Wr[k * 128 + n]);
    }
    if (tid < 128) { xl0_s[tid] = xl0[b * 128 + tid]; att_s[tid] = att[tid]; }
    __syncthreads();                           // the only barrier

    // ---- W_r^T fragments -> 128 VGPRs (all 8 col-tiles)
    short8 bfr[8][4];
#pragma unroll
    for (int nt = 0; nt < 8; ++nt) {
        const int n  = nt * 16 + l15;
        const int sw = (n & 7) << 3;
#pragma unroll
        for (int ks = 0; ks < 4; ++ks)
            bfr[nt][ks] = *(const short8*)&WrT[n * 128 + ((ks * 32 + ksel * 8) ^ sw)];
    }
    float bi8[8];
#pragma unroll
    for (int nt = 0; nt < 8; ++nt) bi8[nt] = br[nt * 16 + l15];

    const size_t rbase = (size_t)b * NROWS + (size_t)wu * (TILES * TROWS);

    // chunk mapping: c = i*64+lane -> row c>>5, 16B-unit u=c&31 (coalesced 1KB/instr)
    float4 pf[8];
    {
        const float* sp = x + rbase * IND;
#pragma unroll
        for (int i = 0; i < 8; ++i) {
            const int c = i * 64 + lane;
            pf[i] = *(const float4*)(sp + (c >> 5) * IND + (c & 31) * 4);
        }
    }

    float Mr = -INFINITY, Sr = 0.f;            // stats for head = ksel
    float Pp[8] = {0.f, 0.f, 0.f, 0.f, 0.f, 0.f, 0.f, 0.f};

    for (int t = 0; t < TILES; ++t) {
        // ---- stage own tile f32 -> slab (gapped cols: col 4u -> (u>>3)*40+(u&7)*4)
#pragma unroll
        for (int i = 0; i < 8; ++i) {
            const int c = i * 64 + lane, u = c & 31;
            *(float4*)&slab[(c >> 5) * SLDS + (u >> 3) * 40 + (u & 7) * 4] = pf[i];
        }
        // ---- A fragments (pack f32->bf16 at read)
        short8 afr[4];
#pragma unroll
        for (int ks = 0; ks < 4; ++ks) {
            float4 lo = *(const float4*)&slab[l15 * SLDS + ks * 40 + ksel * 8];
            float4 hi = *(const float4*)&slab[l15 * SLDS + ks * 40 + ksel * 8 + 4];
            union { short8 s; unsigned u[4]; } uu;
            uu.u[0] = pack2(lo.x, lo.y); uu.u[1] = pack2(lo.z, lo.w);
            uu.u[2] = pack2(hi.x, hi.y); uu.u[3] = pack2(hi.z, hi.w);
            afr[ks] = uu.s;
        }
        // ---- MFMA: 16 rows x 128 cols, K=128
        f32x4 acc[8];
#pragma unroll
        for (int nt = 0; nt < 8; ++nt) acc[nt] = (f32x4){0.f, 0.f, 0.f, 0.f};
#pragma unroll
        for (int nt = 0; nt < 8; ++nt)
#pragma unroll
            for (int ks = 0; ks < 4; ++ks)
                acc[nt] = __builtin_amdgcn_mfma_f32_16x16x32_bf16(
                    afr[ks], bfr[nt][ks], acc[nt], 0, 0, 0);

        // ---- bias + spill (acc dies here; P reads slab later)
#pragma unroll
        for (int nt = 0; nt < 8; ++nt) {
            const int C = (nt >> 1) * 40 + (nt & 1) * 16 + l15;
#pragma unroll
            for (int rg = 0; rg < 4; ++rg)
                slab[(ksel * 4 + rg) * SLDS + C] = acc[nt][rg] + bi8[nt];
        }
        CFENCE();

        // ---- prefetch next tile (in flight through the rest of the epilogue)
        if (t + 1 < TILES) {
            const float* sp = x + (rbase + (size_t)(t + 1) * TROWS) * IND;
#pragma unroll
            for (int i = 0; i < 8; ++i) {
                const int c = i * 64 + lane;
                pf[i] = *(const float4*)(sp + (c >> 5) * IND + (c & 31) * 4);
            }
        }

        // ---- out store: 8 x 1KB contiguous
        {
            float* ob = out + (rbase + (size_t)t * TROWS) * HC;
#pragma unroll
            for (int j = 0; j < 8; ++j) {
                const int row = 2 * j + (lane >> 5), u = lane & 31;
                *(float4*)(ob + (size_t)row * HC + u * 4) =
                    *(const float4*)&slab[row * SLDS + (u >> 3) * 40 + (u & 7) * 4];
            }
        }

        // ---- logits: lane = (row l15, head ksel); 8 LDS float4 reads, no redundancy
        float lg = 0.f;
        {
            const float* vp = &slab[l15 * SLDS + ksel * 40];
            const float* ap = &att_s[ksel * 32];
            const float* qp = &xl0_s[ksel * 32];
#pragma unroll
            for (int c4 = 0; c4 < 32; c4 += 4) {
                float4 xv = *(const float4*)(vp + c4);
                float4 av = *(const float4*)(ap + c4);
                float4 qv = *(const float4*)(qp + c4);
                float v0 = qv.x + xv.x; v0 = v0 > 0.f ? v0 : NEG * v0;
                float v1 = qv.y + xv.y; v1 = v1 > 0.f ? v1 : NEG * v1;
                float v2 = qv.z + xv.z; v2 = v2 > 0.f ? v2 : NEG * v2;
                float v3 = qv.w + xv.w; v3 = v3 > 0.f ? v3 : NEG * v3;
                lg = fmaf(v0, av.x, fmaf(v1, av.y, fmaf(v2, av.z, fmaf(v3, av.w, lg))));
            }
        }
        // ---- group (16-lane) online softmax: 1 expf/lane
        float mx = lg;
        mx = fmaxf(mx, __shfl_xor(mx, 1));
        mx = fmaxf(mx, __shfl_xor(mx, 2));
        mx = fmaxf(mx, __shfl_xor(mx, 4));
        mx = fmaxf(mx, __shfl_xor(mx, 8));
        const float Mn = fmaxf(Mr, mx);
        const float e  = __expf(lg - Mn);       // w for (row l15, head ksel)
        const float sc = __expf(Mr - Mn);       // 0 on first tile
        float st = e;
        st += __shfl_xor(st, 1); st += __shfl_xor(st, 2);
        st += __shfl_xor(st, 4); st += __shfl_xor(st, 8);
        Sr = Sr * sc + st;
        Mr = Mn;

        // ---- gather sc/w for all heads (bpermute)
        float sc4[4], wrh[4][4];
#pragma unroll
        for (int h = 0; h < 4; ++h) sc4[h] = __shfl(sc, h * 16 + l15);
#pragma unroll
        for (int h = 0; h < 4; ++h)
#pragma unroll
            for (int rg = 0; rg < 4; ++rg)
                wrh[h][rg] = __shfl(e, h * 16 + ksel * 4 + rg);

        // ---- P partial update: lane owns cols nt*16+l15, its 4 rows (ksel*4+rg)
#pragma unroll
        for (int nt = 0; nt < 8; ++nt) {
            const int h  = nt >> 1;
            const int Cb = h * 40 + (nt & 1) * 16 + l15;
            float p = 0.f;
#pragma unroll
            for (int rg = 0; rg < 4; ++rg)
                p = fmaf(wrh[h][rg], slab[(ksel * 4 + rg) * SLDS + Cb], p);
            Pp[nt] = Pp[nt] * sc4[h] + p;
        }
    }

    // ---- fold P across ksel groups, write wave partials
#pragma unroll
    for (int nt = 0; nt < 8; ++nt) {
        Pp[nt] += __shfl_xor(Pp[nt], 16);
        Pp[nt] += __shfl_xor(Pp[nt], 32);
    }
    float* pb = part + (size_t)(b * WPB + wu) * PART_STRIDE;
    if (l15 == 0) { pb[ksel] = Mr; pb[4 + ksel] = Sr; }
    if (ksel == 0) {
#pragma unroll
        for (int nt = 0; nt < 8; ++nt) pb[8 + nt * 16 + l15] = Pp[nt];
    }
}

// ---------------- kernel C: combine partials, write center row ---------------
__global__ void gat_final(const float* __restrict__ part, float* __restrict__ out)
{
    const int b = blockIdx.x, t = threadIdx.x;   // 128 threads: t = h*32+c
    const int h = t >> 5;
    const float* pb = part + (size_t)b * WPB * PART_STRIDE;
    float Mg = -INFINITY;
#pragma unroll 4
    for (int i = 0; i < WPB; ++i) Mg = fmaxf(Mg, pb[i * PART_STRIDE + h]);
    float Sg = 0.f, Pg = 0.f;
#pragma unroll 4
    for (int i = 0; i < WPB; ++i) {
        const float sc = __expf(pb[i * PART_STRIDE + h] - Mg);
        Sg += pb[i * PART_STRIDE + 4 + h] * sc;
        Pg  = fmaf(pb[i * PART_STRIDE + 8 + t], sc, Pg);
    }
    out[(size_t)b * NROWS * HC + t] = Pg / Sg;
}

extern "C" void kernel_launch(void* const* d_in, const int* in_sizes, int n_in,
                              void* d_out, int out_size, void* d_ws, size_t ws_size,
                              hipStream_t stream)
{
    const float* x   = (const float*)d_in[0];
    const float* Wl  = (const float*)d_in[1];
    const float* bl  = (const float*)d_in[2];
    const float* Wr  = (const float*)d_in[3];
    const float* br  = (const float*)d_in[4];
    const float* att = (const float*)d_in[5];
    float* out = (float*)d_out;

    float* xl0  = (float*)d_ws;                // 32*128 f32
    float* part = xl0 + BATCH * 128;           // 32*64*136 f32 = 1.1 MB

    gat_center<<<BATCH, 128, 0, stream>>>(x, Wl, bl, xl0);
    gat_main<<<BATCH * 16, 256, 0, stream>>>(x, Wr, br, att, xl0, out, part);
    gat_final<<<BATCH, 128, 0, stream>>>(part, out);
}